// Round 6
// baseline (180.987 us; speedup 1.0000x reference)
//
#include <hip/hip_runtime.h>
#include <hip/hip_bf16.h>

#define B_ROWS 4096
#define D_DIM  512
#define N_ROWS 8192   // 2B
#define BM 128
#define BN 128
#define BKB 128       // K-step in BYTES (= fp8 elements) per loop iteration
#define NBLK (N_ROWS / BM)             // 64 row-blocks
#define NPAIR (NBLK * (NBLK + 1) / 2)  // 2080 upper-tri block pairs

typedef float f32x4 __attribute__((ext_vector_type(4)));
typedef int   v4i   __attribute__((ext_vector_type(4)));
typedef int   v8i   __attribute__((ext_vector_type(8)));

// ---------------------------------------------------------------------------
// Kernel 1: per-pair prep. Block r computes norms, pos[r] (fp32 exact),
// fp8-e4m3 normalized rows Z[r], Z[r+B]; zeroes row_sum and completion ctr.
// ---------------------------------------------------------------------------
__global__ __launch_bounds__(256) void prep_kernel(
    const float* __restrict__ poly, const float* __restrict__ cemb,
    unsigned char* __restrict__ Z, float* __restrict__ row_sum,
    float* __restrict__ pos, unsigned int* __restrict__ counter)
{
    const int r = blockIdx.x;
    const int t = threadIdx.x;
    const float* prow = poly + (size_t)r * D_DIM;
    const float* crow = cemb + (size_t)r * D_DIM;

    const float2 pv = *(const float2*)(prow + 2 * t);
    const float2 cv = *(const float2*)(crow + 2 * t);

    float ssp = pv.x * pv.x + pv.y * pv.y;
    float ssc = cv.x * cv.x + cv.y * cv.y;
    float dt  = pv.x * cv.x + pv.y * cv.y;

    #pragma unroll
    for (int m = 1; m < 64; m <<= 1) {
        ssp += __shfl_xor(ssp, m);
        ssc += __shfl_xor(ssc, m);
        dt  += __shfl_xor(dt,  m);
    }
    __shared__ float red[3][4];
    const int wave = t >> 6;
    if ((t & 63) == 0) { red[0][wave] = ssp; red[1][wave] = ssc; red[2][wave] = dt; }
    __syncthreads();
    ssp = red[0][0] + red[0][1] + red[0][2] + red[0][3];
    ssc = red[1][0] + red[1][1] + red[1][2] + red[1][3];
    dt  = red[2][0] + red[2][1] + red[2][2] + red[2][3];

    const float sp = 1.0f / fmaxf(sqrtf(ssp), 1e-12f);
    const float sc = 1.0f / fmaxf(sqrtf(ssc), 1e-12f);

    unsigned char* zp = Z + (size_t)r * D_DIM;
    unsigned char* zc = Z + (size_t)(r + B_ROWS) * D_DIM;
    const int pk = __builtin_amdgcn_cvt_pk_fp8_f32(pv.x * sp, pv.y * sp, 0, false);
    const int ck = __builtin_amdgcn_cvt_pk_fp8_f32(cv.x * sc, cv.y * sc, 0, false);
    *(unsigned short*)(zp + 2 * t) = (unsigned short)(pk & 0xffff);
    *(unsigned short*)(zc + 2 * t) = (unsigned short)(ck & 0xffff);

    if (t == 0) {
        pos[r] = dt * sp * sc;
        row_sum[2 * r]     = 0.0f;
        row_sum[2 * r + 1] = 0.0f;
        if (r == 0) *counter = 0u;
    }
}

// ---------------------------------------------------------------------------
// Kernel 2: symmetric sim = Z Z^T via mfma_scale_f32_16x16x128_f8f6f4 with
// UNIT scales (fp8 math at 2x the non-scaled rate; layout verified absmax
// 0.0 in rounds 1-5).
//
// Rounds 0-5 law: sim time is a pure function of the VGPR occupancy
// BRACKET (m69: waves/CU halves at 64/128/256 total regs). Every variant
// in the 129-256 bracket (r0 148, r1 216, r4 224, r5 140) = 8 waves/CU =
// 69-94 us, regardless of barriers (8/5/0), LDS (34K/67K/1.5K), or MFMA
// rate. Latency-bound: only resident waves matter.
//
// This version crosses the bracket: 8 waves (512 thr) x 64x32 output per
// wave -> acc[4][2] = 32 AGPR; direct-L2 fragment loads (r5 path: no LDS
// staging, no barriers, no swizzle); live set afr 8 + bfr 16 + ptrs 12 +
// misc -> target total <= 128/wave = 16 waves/CU (2x residency). NO
// min-waves launch-bounds clause (r2/r3: any cap -> 285-500 MB scratch
// spill). MFMA count per block unchanged (exact 64-subtile cover). L2
// traffic ~800 MB total (A 4x-dup, B 2x-dup) = ~23 us floor at 34.5 TB/s.
// Epilogue / fence-free finalize = r3's 8-wave version (verified).
// ---------------------------------------------------------------------------
__global__ __launch_bounds__(512) void sim_kernel(
    const unsigned char* __restrict__ Z, float* __restrict__ row_sum,
    const float* __restrict__ pos, float* __restrict__ out,
    unsigned int* __restrict__ counter)
{
    __shared__ float rAcc[BM];
    __shared__ float cAcc[BN];
    __shared__ unsigned int lastFlag;

    // decode blockIdx.x -> (bi, bj), bi <= bj < 64; C(b) = b*(129-b)/2
    const int t0 = blockIdx.x;
    int bi = (int)((129.0f - sqrtf(16641.0f - 8.0f * (float)t0)) * 0.5f);
    #define CFN(b) ((b) * (129 - (b)) / 2)
    while (CFN(bi + 1) <= t0) ++bi;
    while (CFN(bi) > t0) --bi;
    const int bj = bi + (t0 - CFN(bi));
    #undef CFN

    const int ibase = bi * BM;
    const int jbase = bj * BN;
    const int tid   = threadIdx.x;

    const int wave = tid >> 6;                 // 0..7
    const int lane = tid & 63;
    const int wi = (wave >> 2) * 64;           // 2 row groups of 64
    const int wj = (wave & 3) * 32;            // 4 col groups of 32
    const int quad = lane >> 4;
    const int c    = lane & 15;

    f32x4 acc[4][2] = {};

    // Per-lane fragment base addresses (computed once; K-loop adds k0).
    // Fragment for lane (c,quad), subtile t: bytes
    //   Z[(base + t*16 + c) * 512 + quad*32 + k0 .. +32]
    const unsigned char* aptr[4];
    const unsigned char* bptr[2];
    #pragma unroll
    for (int t = 0; t < 4; ++t)
        aptr[t] = Z + (size_t)(ibase + wi + t * 16 + c) * D_DIM + quad * 32;
    #pragma unroll
    for (int t = 0; t < 2; ++t)
        bptr[t] = Z + (size_t)(jbase + wj + t * 16 + c) * D_DIM + quad * 32;

    #pragma unroll 1
    for (int k0 = 0; k0 < D_DIM; k0 += BKB) {   // 4 iterations, rolled
        v8i bfr[2];
        #pragma unroll
        for (int tj = 0; tj < 2; ++tj) {
            const v4i lo = *(const v4i*)(bptr[tj] + k0);
            const v4i hi = *(const v4i*)(bptr[tj] + k0 + 16);
            bfr[tj] = __builtin_shufflevector(lo, hi, 0, 1, 2, 3, 4, 5, 6, 7);
        }
        #pragma unroll
        for (int ti = 0; ti < 4; ++ti) {
            const v4i lo = *(const v4i*)(aptr[ti] + k0);
            const v4i hi = *(const v4i*)(aptr[ti] + k0 + 16);
            const v8i afr = __builtin_shufflevector(lo, hi, 0, 1, 2, 3, 4, 5, 6, 7);
            #pragma unroll
            for (int tj = 0; tj < 2; ++tj)
                acc[ti][tj] = __builtin_amdgcn_mfma_scale_f32_16x16x128_f8f6f4(
                    afr, bfr[tj], acc[ti][tj],
                    0, 0,                 // cbsz / blgp: fp8 e4m3 both
                    0, 0x7f7f7f7f,        // opsel_a, scale_a = 1.0 (E8M0 127)
                    0, 0x7f7f7f7f);       // opsel_b, scale_b = 1.0
        }
    }

    // ---- Epilogue: strict-upper exp(sim/T), pre-reduced in LDS ----
    if (tid < BM) { rAcc[tid] = 0.0f; cAcc[tid] = 0.0f; }
    __syncthreads();

    const float K2 = 2.885390081777927f;  // 2*log2(e) = 1/(T*ln2)
    float col[2] = {0.0f, 0.0f};
    #pragma unroll
    for (int ti = 0; ti < 4; ++ti) {
        const int li = wi + ti * 16 + quad * 4;
        #pragma unroll
        for (int r = 0; r < 4; ++r) {
            const int gi = ibase + li + r;
            float v = 0.0f;
            #pragma unroll
            for (int tj = 0; tj < 2; ++tj) {
                const int gj = jbase + wj + tj * 16 + c;
                const float e = (gj > gi) ? exp2f(K2 * acc[ti][tj][r]) : 0.0f;
                v += e;
                col[tj] += e;
            }
            v += __shfl_xor(v, 1);
            v += __shfl_xor(v, 2);
            v += __shfl_xor(v, 4);
            v += __shfl_xor(v, 8);
            if (c == 0)
                atomicAdd(&rAcc[li + r], v);
        }
    }
    #pragma unroll
    for (int tj = 0; tj < 2; ++tj) {
        float w = col[tj];
        w += __shfl_xor(w, 16);
        w += __shfl_xor(w, 32);
        if (quad == 0)
            atomicAdd(&cAcc[wj + tj * 16 + c], w);
    }
    __syncthreads();

    if (tid < BM)
        atomicAdd(&row_sum[ibase + tid], rAcc[tid]);
    else if (tid < 2 * BM)
        atomicAdd(&row_sum[jbase + tid - BM], cAcc[tid - BM]);

    // ---- Completion count; last block computes the loss (fence-free) ----
    __syncthreads();   // barrier implies vmcnt(0): this block's atomics issued
    if (tid == 0) {
        unsigned int old = __hip_atomic_fetch_add(
            counter, 1u, __ATOMIC_RELAXED, __HIP_MEMORY_SCOPE_AGENT);
        lastFlag = (old == NPAIR - 1) ? 1u : 0u;
    }
    __syncthreads();
    if (lastFlag) {
        float accL = 0.0f, accP = 0.0f;
        for (int i = tid; i < N_ROWS; i += 512) {
            const float rs = __hip_atomic_load(
                &row_sum[i], __ATOMIC_RELAXED, __HIP_MEMORY_SCOPE_AGENT);
            accL += __logf(rs);
        }
        for (int r = tid; r < B_ROWS; r += 512)
            accP += pos[r];
        #pragma unroll
        for (int m = 1; m < 64; m <<= 1) {
            accL += __shfl_xor(accL, m);
            accP += __shfl_xor(accP, m);
        }
        if (lane == 0) { rAcc[wave] = accL; cAcc[wave] = accP; }
        __syncthreads();
        if (tid == 0) {
            float L = 0.0f, P = 0.0f;
            #pragma unroll
            for (int w = 0; w < 8; ++w) { L += rAcc[w]; P += cAcc[w]; }
            out[0] = (L - 4.0f * P) / (float)N_ROWS;
        }
    }
}

extern "C" void kernel_launch(void* const* d_in, const int* in_sizes, int n_in,
                              void* d_out, int out_size, void* d_ws, size_t ws_size,
                              hipStream_t stream) {
    const float* poly = (const float*)d_in[0];
    const float* cemb = (const float*)d_in[1];

    unsigned char* Z       = (unsigned char*)d_ws;
    float*         row_sum = (float*)((char*)d_ws + (size_t)N_ROWS * D_DIM);
    float*         pos     = row_sum + N_ROWS;
    unsigned int*  counter = (unsigned int*)(pos + B_ROWS);
    float*         out     = (float*)d_out;

    prep_kernel<<<B_ROWS, 256, 0, stream>>>(poly, cemb, Z, row_sum, pos, counter);
    sim_kernel<<<NPAIR, 512, 0, stream>>>(Z, row_sum, pos, out, counter);
}

// Round 7
// 121.016 us; speedup vs baseline: 1.4956x; 1.4956x over previous
//
#include <hip/hip_runtime.h>
#include <hip/hip_bf16.h>

#define B_ROWS 4096
#define D_DIM  512
#define N_ROWS 8192   // 2B
#define BM 128
#define BN 128
#define BKB 128       // K-tile in BYTES (= fp8 elements); row stride 128B, 8x16B granules
#define NBLK (N_ROWS / BM)             // 64 row-blocks
#define NPAIR (NBLK * (NBLK + 1) / 2)  // 2080 upper-tri block pairs

typedef float f32x4 __attribute__((ext_vector_type(4)));
typedef int   v4i   __attribute__((ext_vector_type(4)));
typedef int   v8i   __attribute__((ext_vector_type(8)));

// ---------------------------------------------------------------------------
// Kernel 1: prep, one WAVE per row-pair r (no LDS, no barriers).
// Lane loads p[lane*8..+8] and c[lane*8..+8] (2x float4 each), computes
// partial ssp/ssc/dot, 6-step shuffle butterfly, then packs 8 fp8 e4m3
// per lane (4x cvt_pk) and stores 8 B coalesced. pos[r] fp32-exact.
// Replaces the old 256-thread/2-barrier block version (~constant ~60 us
// of every round's total that sim-side changes never touched).
// ---------------------------------------------------------------------------
__global__ __launch_bounds__(256) void prep_kernel(
    const float* __restrict__ poly, const float* __restrict__ cemb,
    unsigned char* __restrict__ Z, float* __restrict__ row_sum,
    float* __restrict__ pos, unsigned int* __restrict__ counter)
{
    const int wave = threadIdx.x >> 6;
    const int lane = threadIdx.x & 63;
    const int r = blockIdx.x * 4 + wave;          // 1024 blocks x 4 waves

    const float4* prow = (const float4*)(poly + (size_t)r * D_DIM) + lane * 2;
    const float4* crow = (const float4*)(cemb + (size_t)r * D_DIM) + lane * 2;
    const float4 p0 = prow[0], p1 = prow[1];
    const float4 c0 = crow[0], c1 = crow[1];

    float ssp = p0.x*p0.x + p0.y*p0.y + p0.z*p0.z + p0.w*p0.w
              + p1.x*p1.x + p1.y*p1.y + p1.z*p1.z + p1.w*p1.w;
    float ssc = c0.x*c0.x + c0.y*c0.y + c0.z*c0.z + c0.w*c0.w
              + c1.x*c1.x + c1.y*c1.y + c1.z*c1.z + c1.w*c1.w;
    float dt  = p0.x*c0.x + p0.y*c0.y + p0.z*c0.z + p0.w*c0.w
              + p1.x*c1.x + p1.y*c1.y + p1.z*c1.z + p1.w*c1.w;

    #pragma unroll
    for (int m = 1; m < 64; m <<= 1) {
        ssp += __shfl_xor(ssp, m);
        ssc += __shfl_xor(ssc, m);
        dt  += __shfl_xor(dt,  m);
    }

    const float sp = 1.0f / fmaxf(sqrtf(ssp), 1e-12f);
    const float sc = 1.0f / fmaxf(sqrtf(ssc), 1e-12f);

    int2 zp, zc;
    zp.x = __builtin_amdgcn_cvt_pk_fp8_f32(p0.x*sp, p0.y*sp, 0, false)
         | (__builtin_amdgcn_cvt_pk_fp8_f32(p0.z*sp, p0.w*sp, 0, false) << 16);
    zp.y = __builtin_amdgcn_cvt_pk_fp8_f32(p1.x*sp, p1.y*sp, 0, false)
         | (__builtin_amdgcn_cvt_pk_fp8_f32(p1.z*sp, p1.w*sp, 0, false) << 16);
    zc.x = __builtin_amdgcn_cvt_pk_fp8_f32(c0.x*sc, c0.y*sc, 0, false)
         | (__builtin_amdgcn_cvt_pk_fp8_f32(c0.z*sc, c0.w*sc, 0, false) << 16);
    zc.y = __builtin_amdgcn_cvt_pk_fp8_f32(c1.x*sc, c1.y*sc, 0, false)
         | (__builtin_amdgcn_cvt_pk_fp8_f32(c1.z*sc, c1.w*sc, 0, false) << 16);

    *(int2*)(Z + (size_t)r * D_DIM + lane * 8)            = zp;
    *(int2*)(Z + (size_t)(r + B_ROWS) * D_DIM + lane * 8) = zc;

    if (lane == 0) {
        pos[r] = dt * sp * sc;
        row_sum[2 * r]     = 0.0f;
        row_sum[2 * r + 1] = 0.0f;
        if (r == 0) *counter = 0u;
    }
}

// ---------------------------------------------------------------------------
// Kernel 2: symmetric sim = Z Z^T via mfma_scale_f32_16x16x128_f8f6f4 with
// UNIT scales (fp8 math at 2x the non-scaled rate; verified absmax 0.0 in
// rounds 1-6).
//
// Seven data points distilled:
//   - Coalesced global_load_lds staging beats direct per-lane L2 loads:
//     the scattered fragment loads touch ~32 cache lines/instr and the
//     L1/TA path serializes -- r6 (52% occ, no barriers) = 118 us WORSE
//     than r0 (21% occ, staged) = 68.8 us. More waves amplify it.
//   - Within the staged path, time scales with resident waves (12 w/CU
//     -> 68.8; 8 w/CU -> ~95 regardless of barriers/MFMA rate).
//   - Any __launch_bounds__ min-waves cap => 285-500 MB scratch spill.
// => This round: r3's exact verified shape (8 waves x 64x32/wave, staged,
//    single-buffer 32 KB, scaled MFMA) WITHOUT the cap. r6 proved the
//    64x32 shape allocates ~40 arch VGPR naturally; + staging addrs
//    ~50-60 arch + 32 acc = ~82-92 total -> 5-6 waves/SIMD -> 16-24
//    waves/CU on the good (staged) path: 1.3-2x r0's residency.
// Epilogue / fence-free finalize = r3's 8-wave version (verified).
// ---------------------------------------------------------------------------
__global__ __launch_bounds__(512) void sim_kernel(
    const unsigned char* __restrict__ Z, float* __restrict__ row_sum,
    const float* __restrict__ pos, float* __restrict__ out,
    unsigned int* __restrict__ counter)
{
    __shared__ __align__(16) unsigned char As[BM * BKB];   // 16 KB
    __shared__ __align__(16) unsigned char Bs[BN * BKB];   // 16 KB
    __shared__ float rAcc[BM];
    __shared__ float cAcc[BN];
    __shared__ unsigned int lastFlag;

    // decode blockIdx.x -> (bi, bj), bi <= bj < 64; C(b) = b*(129-b)/2
    const int t0 = blockIdx.x;
    int bi = (int)((129.0f - sqrtf(16641.0f - 8.0f * (float)t0)) * 0.5f);
    #define CFN(b) ((b) * (129 - (b)) / 2)
    while (CFN(bi + 1) <= t0) ++bi;
    while (CFN(bi) > t0) --bi;
    const int bj = bi + (t0 - CFN(bi));
    #undef CFN
    const bool diag = (bi == bj);

    const int ibase = bi * BM;
    const int jbase = bj * BN;
    const int tid   = threadIdx.x;

    const int srow = tid >> 3;                 // staging row (0..63) within 64-row group
    const int gchk = (tid & 7) ^ (srow & 7);   // swizzled source granule (16B)

    const int wave = tid >> 6;                 // 0..7
    const int lane = tid & 63;
    const int wi = (wave >> 2) * 64;           // 2 row groups of 64
    const int wj = (wave & 3) * 32;            // 4 col groups of 32
    const int quad = lane >> 4;
    const int c    = lane & 15;

    f32x4 acc[4][2] = {};

    // LDS granule G of row R holds global granule G ^ (R&7); fragment rows
    // have R&7 == c&7. Lane needs global k = quad*32 .. +32 -> granules
    // 2*quad, 2*quad+1 at swizzled slots:
    const int sg0 = (((quad << 1)    ) ^ (c & 7)) * 16;
    const int sg1 = (((quad << 1) | 1) ^ (c & 7)) * 16;

    #pragma unroll 1
    for (int k0 = 0; k0 < D_DIM; k0 += BKB) {   // 4 iterations, rolled
        #pragma unroll
        for (int it = 0; it < 2; ++it) {        // 512 thr x 16B x 2 = 16 KB
            const int row = it * 64 + srow;
            const unsigned char* ga = Z + (size_t)(ibase + row) * D_DIM + k0 + gchk * 16;
            __builtin_amdgcn_global_load_lds(
                (const __attribute__((address_space(1))) void*)ga,
                (__attribute__((address_space(3))) void*)(As + it * 8192 + tid * 16),
                16, 0, 0);
        }
        if (!diag) {
            #pragma unroll
            for (int it = 0; it < 2; ++it) {
                const int row = it * 64 + srow;
                const unsigned char* gb = Z + (size_t)(jbase + row) * D_DIM + k0 + gchk * 16;
                __builtin_amdgcn_global_load_lds(
                    (const __attribute__((address_space(1))) void*)gb,
                    (__attribute__((address_space(3))) void*)(Bs + it * 8192 + tid * 16),
                    16, 0, 0);
            }
        }
        __syncthreads();

        const unsigned char* bb = diag ? As : Bs;

        v8i bfr[2];
        #pragma unroll
        for (int tj = 0; tj < 2; ++tj) {
            const unsigned char* base = bb + (wj + tj * 16 + c) * BKB;
            const v4i lo = *(const v4i*)(base + sg0);
            const v4i hi = *(const v4i*)(base + sg1);
            bfr[tj] = __builtin_shufflevector(lo, hi, 0, 1, 2, 3, 4, 5, 6, 7);
        }
        #pragma unroll
        for (int ti = 0; ti < 4; ++ti) {
            const unsigned char* base = As + (wi + ti * 16 + c) * BKB;
            const v4i lo = *(const v4i*)(base + sg0);
            const v4i hi = *(const v4i*)(base + sg1);
            const v8i afr = __builtin_shufflevector(lo, hi, 0, 1, 2, 3, 4, 5, 6, 7);
            #pragma unroll
            for (int tj = 0; tj < 2; ++tj)
                acc[ti][tj] = __builtin_amdgcn_mfma_scale_f32_16x16x128_f8f6f4(
                    afr, bfr[tj], acc[ti][tj],
                    0, 0,                 // cbsz / blgp: fp8 e4m3 both
                    0, 0x7f7f7f7f,        // opsel_a, scale_a = 1.0 (E8M0 127)
                    0, 0x7f7f7f7f);       // opsel_b, scale_b = 1.0
        }
        __syncthreads();
    }

    // ---- Epilogue: strict-upper exp(sim/T), pre-reduced in LDS ----
    if (tid < BM) { rAcc[tid] = 0.0f; cAcc[tid] = 0.0f; }
    __syncthreads();

    const float K2 = 2.885390081777927f;  // 2*log2(e) = 1/(T*ln2)
    float col[2] = {0.0f, 0.0f};
    #pragma unroll
    for (int ti = 0; ti < 4; ++ti) {
        const int li = wi + ti * 16 + quad * 4;
        #pragma unroll
        for (int r = 0; r < 4; ++r) {
            const int gi = ibase + li + r;
            float v = 0.0f;
            #pragma unroll
            for (int tj = 0; tj < 2; ++tj) {
                const int gj = jbase + wj + tj * 16 + c;
                const float e = (gj > gi) ? exp2f(K2 * acc[ti][tj][r]) : 0.0f;
                v += e;
                col[tj] += e;
            }
            v += __shfl_xor(v, 1);
            v += __shfl_xor(v, 2);
            v += __shfl_xor(v, 4);
            v += __shfl_xor(v, 8);
            if (c == 0)
                atomicAdd(&rAcc[li + r], v);
        }
    }
    #pragma unroll
    for (int tj = 0; tj < 2; ++tj) {
        float w = col[tj];
        w += __shfl_xor(w, 16);
        w += __shfl_xor(w, 32);
        if (quad == 0)
            atomicAdd(&cAcc[wj + tj * 16 + c], w);
    }
    __syncthreads();

    if (tid < BM)
        atomicAdd(&row_sum[ibase + tid], rAcc[tid]);
    else if (tid < 2 * BM)
        atomicAdd(&row_sum[jbase + tid - BM], cAcc[tid - BM]);

    // ---- Completion count; last block computes the loss (fence-free) ----
    __syncthreads();   // barrier implies vmcnt(0): this block's atomics issued
    if (tid == 0) {
        unsigned int old = __hip_atomic_fetch_add(
            counter, 1u, __ATOMIC_RELAXED, __HIP_MEMORY_SCOPE_AGENT);
        lastFlag = (old == NPAIR - 1) ? 1u : 0u;
    }
    __syncthreads();
    if (lastFlag) {
        float accL = 0.0f, accP = 0.0f;
        for (int i = tid; i < N_ROWS; i += 512) {
            const float rs = __hip_atomic_load(
                &row_sum[i], __ATOMIC_RELAXED, __HIP_MEMORY_SCOPE_AGENT);
            accL += __logf(rs);
        }
        for (int r = tid; r < B_ROWS; r += 512)
            accP += pos[r];
        #pragma unroll
        for (int m = 1; m < 64; m <<= 1) {
            accL += __shfl_xor(accL, m);
            accP += __shfl_xor(accP, m);
        }
        if (lane == 0) { rAcc[wave] = accL; cAcc[wave] = accP; }
        __syncthreads();
        if (tid == 0) {
            float L = 0.0f, P = 0.0f;
            #pragma unroll
            for (int w = 0; w < 8; ++w) { L += rAcc[w]; P += cAcc[w]; }
            out[0] = (L - 4.0f * P) / (float)N_ROWS;
        }
    }
}

extern "C" void kernel_launch(void* const* d_in, const int* in_sizes, int n_in,
                              void* d_out, int out_size, void* d_ws, size_t ws_size,
                              hipStream_t stream) {
    const float* poly = (const float*)d_in[0];
    const float* cemb = (const float*)d_in[1];

    unsigned char* Z       = (unsigned char*)d_ws;
    float*         row_sum = (float*)((char*)d_ws + (size_t)N_ROWS * D_DIM);
    float*         pos     = row_sum + N_ROWS;
    unsigned int*  counter = (unsigned int*)(pos + B_ROWS);
    float*         out     = (float*)d_out;

    prep_kernel<<<B_ROWS / 4, 256, 0, stream>>>(poly, cemb, Z, row_sum, pos, counter);
    sim_kernel<<<NPAIR, 512, 0, stream>>>(Z, row_sum, pos, out, counter);
}